// Round 1
// baseline (23.774 us; speedup 1.0000x reference)
//
#include <hip/hip_runtime.h>

// KAConv: out[b,f,h,w] = sum_{c,p} P_fcp(v) / (1 + |Q_fcp(v)|),
//   v = x[b,c,h+i-1,w+j-1] (zero pad), p = i*3+j
// Shapes: x[4,16,64,64], A[16,16,9,6], Bc[16,16,9,4], out[4,16,64,64], all f32.

#define BB   4
#define CIN  16
#define COUT 16
#define HH   64
#define WW   64

__global__ __launch_bounds__(256) void KAConv_kernel(
    const float* __restrict__ x,    // [B,C,H,W]
    const float* __restrict__ A,    // [F,C,9,6]
    const float* __restrict__ Bc,   // [F,C,9,4]
    float* __restrict__ out)        // [B,F,H,W]
{
    // grid = B * F * (H/4); block = 256 threads = 4 rows x 64 cols
    const int blk   = blockIdx.x;
    const int htile = blk & 15;          // H/4 = 16 tiles
    const int f     = (blk >> 4) & 15;   // COUT = 16
    const int b     = blk >> 8;

    const int t = threadIdx.x;
    const int w = t & 63;
    const int h = (htile << 2) + (t >> 6);

    const float* __restrict__ xb = x  + b * (CIN * HH * WW);
    const float* __restrict__ Af = A  + f * (CIN * 9 * 6);
    const float* __restrict__ Bf = Bc + f * (CIN * 9 * 4);

    float acc = 0.0f;

    for (int c = 0; c < CIN; ++c) {
        const float* __restrict__ xc = xb + c * (HH * WW);

        // 3x3 window with zero padding
        float v[9];
        #pragma unroll
        for (int i = 0; i < 3; ++i) {
            const int hh = h + i - 1;
            #pragma unroll
            for (int j = 0; j < 3; ++j) {
                const int ww2 = w + j - 1;
                const bool ok = (hh >= 0) & (hh < HH) & (ww2 >= 0) & (ww2 < WW);
                v[i * 3 + j] = ok ? xc[hh * WW + ww2] : 0.0f;
            }
        }

        const float* __restrict__ Ac = Af + c * (9 * 6);   // wave-uniform -> s_load
        const float* __restrict__ Bq = Bf + c * (9 * 4);

        #pragma unroll
        for (int p = 0; p < 9; ++p) {
            const float vv = v[p];
            const float* __restrict__ a  = Ac + p * 6;
            const float* __restrict__ bq = Bq + p * 4;

            // P = a0 + v*(a1 + v*(a2 + v*(a3 + v*(a4 + v*a5))))
            float P = a[5];
            P = fmaf(P, vv, a[4]);
            P = fmaf(P, vv, a[3]);
            P = fmaf(P, vv, a[2]);
            P = fmaf(P, vv, a[1]);
            P = fmaf(P, vv, a[0]);

            // Qs = b1*v + b2*v^2 + b3*v^3 + b4*v^4
            float Qs = bq[3];
            Qs = fmaf(Qs, vv, bq[2]);
            Qs = fmaf(Qs, vv, bq[1]);
            Qs = fmaf(Qs, vv, bq[0]);
            Qs *= vv;

            const float Q = 1.0f + fabsf(Qs);
            acc = fmaf(P, __builtin_amdgcn_rcpf(Q), acc);
        }
    }

    out[((b * COUT + f) * HH + h) * WW + w] = acc;
}

extern "C" void kernel_launch(void* const* d_in, const int* in_sizes, int n_in,
                              void* d_out, int out_size, void* d_ws, size_t ws_size,
                              hipStream_t stream) {
    const float* x  = (const float*)d_in[0];
    const float* A  = (const float*)d_in[1];
    const float* Bc = (const float*)d_in[2];
    float* out = (float*)d_out;

    const int grid = BB * COUT * (HH / 4);   // 1024 blocks
    KAConv_kernel<<<grid, 256, 0, stream>>>(x, A, Bc, out);
}

// Round 2
// 22.392 us; speedup vs baseline: 1.0617x; 1.0617x over previous
//
#include <hip/hip_runtime.h>

// KAConv: out[b,f,h,w] = sum_{c,p} P_fcp(v) / (1 + |Q_fcp(v)|),
//   v = x[b,c,h+i-1,w+j-1] (zero pad), p = i*3+j
// Shapes: x[4,16,64,64], A[16,16,9,6], Bc[16,16,9,4], out[4,16,64,64], all f32.
//
// Round 2: 2 pixels (h-rows) per thread. One wave = one full W row (64 lanes);
// each wave owns 2 consecutive rows -> 4 window rows x 3 col-offsets = 12
// loads feed 18 windows, and each 90-dword uniform coefficient block feeds
// 2x the FMA work (amortizes the per-c s_load wait).

#define BB   4
#define CIN  16
#define COUT 16
#define HH   64
#define WW   64

__global__ __launch_bounds__(256) void KAConv_kernel(
    const float* __restrict__ x,    // [B,C,H,W]
    const float* __restrict__ A,    // [F,C,9,6]
    const float* __restrict__ Bc,   // [F,C,9,4]
    float* __restrict__ out)        // [B,F,H,W]
{
    // grid = b(4) x rowtile(8) x f(16) = 512 blocks; block = 256 = 4 waves.
    const int blk   = blockIdx.x;
    const int f     = blk & 15;
    const int rtile = (blk >> 4) & 7;
    const int b     = blk >> 7;

    const int t    = threadIdx.x;
    const int w    = t & 63;        // lane = w column
    const int warp = t >> 6;        // 0..3
    const int r0   = (rtile << 3) + (warp << 1);  // this thread's first row
    const int r1   = r0 + 1;

    const float* __restrict__ xb = x  + b * (CIN * HH * WW);
    const float* __restrict__ Af = A  + f * (CIN * 9 * 6);
    const float* __restrict__ Bf = Bc + f * (CIN * 9 * 4);

    float acc0 = 0.0f, acc1 = 0.0f;

    for (int c = 0; c < CIN; ++c) {
        const float* __restrict__ xc = xb + c * (HH * WW);

        // 4 shared window rows (r0-1 .. r0+2) x 3 col offsets, zero-padded.
        float vv[4][3];
        #pragma unroll
        for (int ri = 0; ri < 4; ++ri) {
            const int hh  = r0 - 1 + ri;
            const bool okh = (hh >= 0) & (hh < HH);
            #pragma unroll
            for (int j = 0; j < 3; ++j) {
                const int wj = w + j - 1;
                const bool ok = okh & (wj >= 0) & (wj < WW);
                vv[ri][j] = ok ? xc[hh * WW + wj] : 0.0f;
            }
        }

        const float* __restrict__ Ac = Af + c * 54;   // uniform -> s_load
        const float* __restrict__ Bq = Bf + c * 36;

        #pragma unroll
        for (int p = 0; p < 9; ++p) {
            const int i = p / 3;
            const int j = p % 3;
            const float va = vv[i][j];       // window value for row r0
            const float vb = vv[i + 1][j];   // window value for row r1
            const float* __restrict__ a  = Ac + p * 6;
            const float* __restrict__ bq = Bq + p * 4;

            // P(v) = a0 + v*(a1 + v*(a2 + v*(a3 + v*(a4 + v*a5))))
            float P0 = a[5], P1 = a[5];
            P0 = fmaf(P0, va, a[4]);  P1 = fmaf(P1, vb, a[4]);
            P0 = fmaf(P0, va, a[3]);  P1 = fmaf(P1, vb, a[3]);
            P0 = fmaf(P0, va, a[2]);  P1 = fmaf(P1, vb, a[2]);
            P0 = fmaf(P0, va, a[1]);  P1 = fmaf(P1, vb, a[1]);
            P0 = fmaf(P0, va, a[0]);  P1 = fmaf(P1, vb, a[0]);

            // Qs(v) = v*(b1 + v*(b2 + v*(b3 + v*b4)))
            float q0 = bq[3], q1 = bq[3];
            q0 = fmaf(q0, va, bq[2]); q1 = fmaf(q1, vb, bq[2]);
            q0 = fmaf(q0, va, bq[1]); q1 = fmaf(q1, vb, bq[1]);
            q0 = fmaf(q0, va, bq[0]); q1 = fmaf(q1, vb, bq[0]);
            q0 *= va;                 q1 *= vb;

            const float d0 = 1.0f + fabsf(q0);   // v_add_f32 D, 1.0, |q|
            const float d1 = 1.0f + fabsf(q1);
            acc0 = fmaf(P0, __builtin_amdgcn_rcpf(d0), acc0);
            acc1 = fmaf(P1, __builtin_amdgcn_rcpf(d1), acc1);
        }
    }

    float* __restrict__ of = out + ((b * COUT + f) * HH) * WW + w;
    of[r0 * WW] = acc0;
    of[r1 * WW] = acc1;
}

extern "C" void kernel_launch(void* const* d_in, const int* in_sizes, int n_in,
                              void* d_out, int out_size, void* d_ws, size_t ws_size,
                              hipStream_t stream) {
    const float* x  = (const float*)d_in[0];
    const float* A  = (const float*)d_in[1];
    const float* Bc = (const float*)d_in[2];
    float* out = (float*)d_out;

    const int grid = BB * (HH / 8) * COUT;   // 4 * 8 * 16 = 512 blocks
    KAConv_kernel<<<grid, 256, 0, stream>>>(x, A, Bc, out);
}